// Round 5
// baseline (55.724 us; speedup 1.0000x reference)
//
#include <hip/hip_runtime.h>
#include <stdint.h>

// Problem constants
#define B_N   32768
#define D_IN  35
#define NJ    12
#define NQ    7
#define NO    5
#define QO    35
#define TILE  64                       // samples per block
#define MAXSLOTS (B_N + NJ*TILE)       // 33536 padded permutation slots
#define MAXT     (MAXSLOTS/TILE)       // 524 tiles max

typedef __bf16  v8bf  __attribute__((ext_vector_type(8)));
typedef float   f32x4 __attribute__((ext_vector_type(4)));

__device__ __forceinline__ unsigned short f2bf(float f) {
    unsigned int u = __builtin_bit_cast(unsigned int, f);
    u += 0x7FFFu + ((u >> 16) & 1u);   // round-to-nearest-even
    return (unsigned short)(u >> 16);
}
__device__ __forceinline__ unsigned int pack2(float a, float b) {
    return (unsigned int)f2bf(a) | ((unsigned int)f2bf(b) << 16);
}

// ---------------------------------------------------------------------------
// Kernel 1: combine shared+expert weights into bf16 (ones-col folded into f32
// biases). Block 0 additionally: atomic-free register histogram of ids,
// padded prefix scan, tile table, and -1 fill of perm pad slots.
// w1c: [12][256][64] (k>=35 zero)   w2c: [12][256][256]   vc: [12][48][256]
// ---------------------------------------------------------------------------
__global__ void k_prep(const int* __restrict__ ids,
                       const float* __restrict__ W1_w, const float* __restrict__ W1_b,
                       const float* __restrict__ W2_w, const float* __restrict__ W2_b,
                       const float* __restrict__ W1a_w, const float* __restrict__ W1a_b,
                       const float* __restrict__ W2a_w, const float* __restrict__ W2a_b,
                       const float* __restrict__ V_w,  const float* __restrict__ V_b,
                       const float* __restrict__ Va_w, const float* __restrict__ Va_b,
                       unsigned short* __restrict__ w1c, unsigned short* __restrict__ w2c,
                       unsigned short* __restrict__ vc,
                       float* __restrict__ bias1, float* __restrict__ bias2,
                       float* __restrict__ biasv,
                       int* __restrict__ cursor, int* __restrict__ ntiles,
                       int* __restrict__ tileExpert, int* __restrict__ perm)
{
    const int tid = blockIdx.x * blockDim.x + threadIdx.x;
    const int nth = gridDim.x * blockDim.x;

    // w2c: 12*256*64 quads
    for (int q = tid; q < NJ * 256 * 64; q += nth) {
        int k4 = (q & 63) << 2, h = (q >> 6) & 255, jj = q >> 14;
        const float* a = &W2_w[h * 257 + k4];
        const float* b = &W2a_w[(jj * 256 + h) * 257 + k4];
        ushort4 o;
        o.x = f2bf(a[0] + b[0]); o.y = f2bf(a[1] + b[1]);
        o.z = f2bf(a[2] + b[2]); o.w = f2bf(a[3] + b[3]);
        *(ushort4*)&w2c[(size_t)q << 2] = o;
    }
    // w1c: 12*256*16 quads (k padded to 64)
    for (int q = tid; q < NJ * 256 * 16; q += nth) {
        int k4 = (q & 15) << 2, h = (q >> 4) & 255, jj = q >> 12;
        ushort4 o;
        float v[4];
#pragma unroll
        for (int e = 0; e < 4; ++e) {
            int k = k4 + e;
            v[e] = (k < D_IN) ? (W1_w[h * 36 + k] + W1a_w[(jj * 256 + h) * 36 + k]) : 0.f;
        }
        o.x = f2bf(v[0]); o.y = f2bf(v[1]); o.z = f2bf(v[2]); o.w = f2bf(v[3]);
        *(ushort4*)&w1c[(size_t)q << 2] = o;
    }
    // vc: 12*48*64 quads
    for (int q = tid; q < NJ * 48 * 64; q += nth) {
        int k4 = (q & 63) << 2, qo = (q >> 6) % 48, jj = q / (48 * 64);
        ushort4 o;
        if (qo < QO) {
            const float* a = &V_w[qo * 257 + k4];
            const float* b = &Va_w[(jj * QO + qo) * 257 + k4];
            o.x = f2bf(a[0] + b[0]); o.y = f2bf(a[1] + b[1]);
            o.z = f2bf(a[2] + b[2]); o.w = f2bf(a[3] + b[3]);
        } else {
            o.x = o.y = o.z = o.w = 0;
        }
        *(ushort4*)&vc[(size_t)q << 2] = o;
    }
    // biases (fold ones-column)
    for (int i = tid; i < NJ * 256; i += nth) {
        int h = i & 255, jj = i >> 8;
        bias1[i] = W1_w[h * 36 + 35] + W1a_w[(jj * 256 + h) * 36 + 35] + W1_b[h] + W1a_b[i];
        bias2[i] = W2_w[h * 257 + 256] + W2a_w[(jj * 256 + h) * 257 + 256] + W2_b[h] + W2a_b[i];
    }
    for (int i = tid; i < NJ * 48; i += nth) {
        int qo = i % 48, jj = i / 48;
        float v = 0.f;
        if (qo < QO) v = V_w[qo * 257 + 256] + Va_w[(jj * QO + qo) * 257 + 256]
                       + V_b[qo] + Va_b[jj * QO + qo];
        biasv[i] = v;
    }

    // ---- block 0 only: atomic-free histogram + padded scan + tables ----
    if (blockIdx.x == 0) {
        __shared__ int lh[NJ];
        __shared__ int s_cur[NJ], s_cnt[NJ], s_nt[NJ], tb[NJ + 1];
        const int lt = threadIdx.x;
        if (lt < NJ) lh[lt] = 0;
        __syncthreads();
        // register counters (compile-time indices -> VGPRs), int4 loads
        int cnt[NJ];
#pragma unroll
        for (int j = 0; j < NJ; ++j) cnt[j] = 0;
        const int4* ids4 = (const int4*)ids;
        for (int i = lt; i < B_N / 4; i += 256) {
            int4 v = ids4[i];
#pragma unroll
            for (int j = 0; j < NJ; ++j)
                cnt[j] += (v.x == j) + (v.y == j) + (v.z == j) + (v.w == j);
        }
        // wave-level shuffle reduce, 12 LDS atomics per wave only
#pragma unroll
        for (int j = 0; j < NJ; ++j) {
            int c = cnt[j];
            c += __shfl_xor(c, 1);  c += __shfl_xor(c, 2);  c += __shfl_xor(c, 4);
            c += __shfl_xor(c, 8);  c += __shfl_xor(c, 16); c += __shfl_xor(c, 32);
            if ((lt & 63) == 0 && c) atomicAdd(&lh[j], c);
        }
        __syncthreads();
        if (lt == 0) {
            int off = 0, t = 0;
            for (int j = 0; j < NJ; ++j) {
                int c = lh[j];
                int nt = (c + TILE - 1) / TILE;
                cursor[j] = off;
                s_cur[j] = off; s_cnt[j] = c; s_nt[j] = nt; tb[j] = t;
                t += nt;
                off += nt * TILE;
            }
            tb[NJ] = t;
            ntiles[0] = t;
        }
        __syncthreads();
        const int ntot = tb[NJ];
        for (int tt = lt; tt < ntot; tt += 256) {
            int j = 0;
            while (tb[j + 1] <= tt) ++j;
            tileExpert[tt] = j;
        }
        // pad-slot fill (<=63 per expert)
        for (int p = lt; p < NJ * TILE; p += 256) {
            int j = p / TILE, o = p % TILE;
            int c = s_cnt[j];
            int padN = s_nt[j] * TILE - c;
            if (o < padN) perm[s_cur[j] + c + o] = -1;
        }
    }
}

// ---------------------------------------------------------------------------
// Kernel 2: scatter sample indices into expert-sorted slots (order-free).
// ---------------------------------------------------------------------------
__global__ void k_scatter(const int* __restrict__ ids, int* __restrict__ cursor,
                          int* __restrict__ perm)
{
    __shared__ int lh[NJ], lbase[NJ];
    const int b = blockIdx.x * blockDim.x + threadIdx.x;
    if (threadIdx.x < NJ) lh[threadIdx.x] = 0;
    __syncthreads();
    int id = 0, rank = 0;
    if (b < B_N) { id = ids[b]; rank = atomicAdd(&lh[id], 1); }
    __syncthreads();
    if (threadIdx.x < NJ)
        lbase[threadIdx.x] = lh[threadIdx.x] ? atomicAdd(&cursor[threadIdx.x], lh[threadIdx.x]) : 0;
    __syncthreads();
    if (b < B_N) perm[lbase[id] + rank] = b;
}

// ---------------------------------------------------------------------------
// Kernel 3: fused MLP. Block = 64 samples (one expert), 8 waves (512 thr);
// wave owns a 32-row slice of the N-dim for layers 1-2; waves 0-2 own the
// 48 head rows. 518 blocks ~= 2/CU -> whole grid resident. Weight fragments
// register-prefetched across barriers.
// MFMA 16x16x32 bf16 layouts:
//   A: lane holds A[lane&15][(lane>>4)*8+e]      (weights = A, rows)
//   B: lane holds B[(lane>>4)*8+e][lane&15]      (samples = B, cols)
//   D: col=lane&15 (sample), row=(lane>>4)*4+r   (output row)
// ---------------------------------------------------------------------------
__global__ __launch_bounds__(512, 4) void k_main(
    const float* __restrict__ x, float* __restrict__ out,
    const int* __restrict__ perm, const int* __restrict__ ntiles,
    const int* __restrict__ tileExpert,
    const unsigned short* __restrict__ w1c, const unsigned short* __restrict__ w2c,
    const unsigned short* __restrict__ vc,
    const float* __restrict__ bias1, const float* __restrict__ bias2,
    const float* __restrict__ biasv)
{
    __shared__ __align__(16) unsigned short s_z1[TILE][264];   // z1, then z2
    __shared__ __align__(16) union {
        unsigned short xb[TILE][72];   // bf16 input tile (dead after layer 1)
        float          lg[TILE][40];   // logits (born at heads)
    } s_u;
    __shared__ int s_rows[TILE];

    const int nt  = ntiles[0];
    const int bid = blockIdx.x;
    if (bid >= nt) return;

    // m204 bijective XCD swizzle: contiguous (expert-sorted) chunk per XCD.
    const int q8 = nt >> 3, r8 = nt & 7;
    const int xcd = bid & 7, idx = bid >> 3;
    const int lbid = (xcd < r8 ? xcd * (q8 + 1) : r8 * (q8 + 1) + (xcd - r8) * q8) + idx;

    const int tid  = threadIdx.x;
    const int lane = tid & 63;
    const int wave = tid >> 6;        // 0..7
    const int l16  = lane & 15;
    const int lk   = lane >> 4;
    const int j    = tileExpert[lbid];

    // ---- prefetch this wave's layer-1 A fragments (rows wave*32..+32) ----
    const unsigned short* w1p = w1c + ((size_t)j << 14) + (size_t)(wave * 32) * 64;
    v8bf w1a0[2], w1a1[2];
#pragma unroll
    for (int t = 0; t < 2; ++t) {
        const unsigned short* rp = w1p + (t * 16 + l16) * 64;
        w1a0[t] = *(const v8bf*)&rp[lk * 8];
        w1a1[t] = *(const v8bf*)&rp[32 + lk * 8];
    }

    if (tid < TILE) s_rows[tid] = perm[lbid * TILE + tid];
    for (int i = tid; i < TILE * 36; i += 512) ((unsigned int*)s_u.xb)[i] = 0u;
    __syncthreads();

    for (int i = tid; i < TILE * D_IN; i += 512) {
        int s = i / D_IN, k = i - s * D_IN;
        int r = s_rows[s];
        s_u.xb[s][k] = f2bf(r >= 0 ? x[(size_t)r * D_IN + k] : 0.f);
    }
    __syncthreads();

    const f32x4 vz = {0.f, 0.f, 0.f, 0.f};

    // ---- layer 1: z1[s][h] = relu(W1c[h]·xb[s] + b1[h]), wave owns 32 h ----
    {
        v8bf b1[4][2];
#pragma unroll
        for (int mt = 0; mt < 4; ++mt) {
            b1[mt][0] = *(const v8bf*)&s_u.xb[mt * 16 + l16][lk * 8];
            b1[mt][1] = *(const v8bf*)&s_u.xb[mt * 16 + l16][32 + lk * 8];
        }
        f32x4 acc[2][4];
#pragma unroll
        for (int t = 0; t < 2; ++t)
#pragma unroll
            for (int mt = 0; mt < 4; ++mt) acc[t][mt] = vz;
#pragma unroll
        for (int t = 0; t < 2; ++t) {
#pragma unroll
            for (int mt = 0; mt < 4; ++mt) {
                acc[t][mt] = __builtin_amdgcn_mfma_f32_16x16x32_bf16(w1a0[t], b1[mt][0], acc[t][mt], 0, 0, 0);
                acc[t][mt] = __builtin_amdgcn_mfma_f32_16x16x32_bf16(w1a1[t], b1[mt][1], acc[t][mt], 0, 0, 0);
            }
        }
        // prefetch layer-2 hc=0 A fragments before the barrier
        const unsigned short* w2p = w2c + ((size_t)j << 16) + (size_t)(wave * 32) * 256;
        v8bf a2pre[2];
#pragma unroll
        for (int gt = 0; gt < 2; ++gt)
            a2pre[gt] = *(const v8bf*)&w2p[(gt * 16 + l16) * 256 + lk * 8];

#pragma unroll
        for (int t = 0; t < 2; ++t) {
            f32x4 bz = *(const f32x4*)&bias1[j * 256 + wave * 32 + t * 16 + lk * 4];
#pragma unroll
            for (int mt = 0; mt < 4; ++mt) {
                float v0 = acc[t][mt][0] + bz[0], v1 = acc[t][mt][1] + bz[1];
                float v2 = acc[t][mt][2] + bz[2], v3 = acc[t][mt][3] + bz[3];
                v0 = v0 > 0.f ? v0 : 0.f; v1 = v1 > 0.f ? v1 : 0.f;
                v2 = v2 > 0.f ? v2 : 0.f; v3 = v3 > 0.f ? v3 : 0.f;
                uint2 pk; pk.x = pack2(v0, v1); pk.y = pack2(v2, v3);
                *(uint2*)&s_z1[mt * 16 + l16][wave * 32 + t * 16 + lk * 4] = pk;
            }
        }
        __syncthreads();

        // ---- layer 2: z2 = relu(z1 @ W2c^T + b2), wave owns 32 g-rows ----
        f32x4 acc2[2][4];
#pragma unroll
        for (int gt = 0; gt < 2; ++gt)
#pragma unroll
            for (int mt = 0; mt < 4; ++mt) acc2[gt][mt] = vz;
        {   // hc = 0 (prefetched A)
            v8bf bb[4];
#pragma unroll
            for (int mt = 0; mt < 4; ++mt)
                bb[mt] = *(const v8bf*)&s_z1[mt * 16 + l16][lk * 8];
#pragma unroll
            for (int gt = 0; gt < 2; ++gt)
#pragma unroll
                for (int mt = 0; mt < 4; ++mt)
                    acc2[gt][mt] = __builtin_amdgcn_mfma_f32_16x16x32_bf16(a2pre[gt], bb[mt], acc2[gt][mt], 0, 0, 0);
        }
#pragma unroll 1
        for (int hc = 1; hc < 8; ++hc) {
            v8bf bb[4];
#pragma unroll
            for (int mt = 0; mt < 4; ++mt)
                bb[mt] = *(const v8bf*)&s_z1[mt * 16 + l16][hc * 32 + lk * 8];
#pragma unroll
            for (int gt = 0; gt < 2; ++gt) {
                v8bf a = *(const v8bf*)&w2p[(gt * 16 + l16) * 256 + hc * 32 + lk * 8];
#pragma unroll
                for (int mt = 0; mt < 4; ++mt)
                    acc2[gt][mt] = __builtin_amdgcn_mfma_f32_16x16x32_bf16(a, bb[mt], acc2[gt][mt], 0, 0, 0);
            }
        }
        // prefetch heads gc=0 A fragment before the barrier
        const unsigned short* vp = vc + (size_t)j * 12288 + (size_t)(wave * 16) * 256;
        v8bf a3pre;
        if (wave < 3) a3pre = *(const v8bf*)&vp[l16 * 256 + lk * 8];

        __syncthreads();   // all waves done READING z1 -> safe to overwrite
#pragma unroll
        for (int gt = 0; gt < 2; ++gt) {
            f32x4 bz = *(const f32x4*)&bias2[j * 256 + wave * 32 + gt * 16 + lk * 4];
#pragma unroll
            for (int mt = 0; mt < 4; ++mt) {
                float v0 = acc2[gt][mt][0] + bz[0], v1 = acc2[gt][mt][1] + bz[1];
                float v2 = acc2[gt][mt][2] + bz[2], v3 = acc2[gt][mt][3] + bz[3];
                v0 = v0 > 0.f ? v0 : 0.f; v1 = v1 > 0.f ? v1 : 0.f;
                v2 = v2 > 0.f ? v2 : 0.f; v3 = v3 > 0.f ? v3 : 0.f;
                uint2 pk; pk.x = pack2(v0, v1); pk.y = pack2(v2, v3);
                *(uint2*)&s_z1[mt * 16 + l16][wave * 32 + gt * 16 + lk * 4] = pk;
            }
        }
        __syncthreads();

        // ---- heads: logits[s][qo] = Vc[qo]·z2[s] + bv[qo]; waves 0..2 ----
        if (wave < 3) {
            f32x4 av[4] = {vz, vz, vz, vz};
            {   // gc = 0 (prefetched A)
#pragma unroll
                for (int mt = 0; mt < 4; ++mt) {
                    v8bf bb = *(const v8bf*)&s_z1[mt * 16 + l16][lk * 8];
                    av[mt] = __builtin_amdgcn_mfma_f32_16x16x32_bf16(a3pre, bb, av[mt], 0, 0, 0);
                }
            }
#pragma unroll 1
            for (int gc = 1; gc < 8; ++gc) {
                v8bf a = *(const v8bf*)&vp[l16 * 256 + gc * 32 + lk * 8];
#pragma unroll
                for (int mt = 0; mt < 4; ++mt) {
                    v8bf bb = *(const v8bf*)&s_z1[mt * 16 + l16][gc * 32 + lk * 8];
                    av[mt] = __builtin_amdgcn_mfma_f32_16x16x32_bf16(a, bb, av[mt], 0, 0, 0);
                }
            }
            int qb = wave * 16 + lk * 4;
            if (qb < 36) {   // rows >= 35 never read by softmax
                f32x4 bz = *(const f32x4*)&biasv[j * 48 + qb];
#pragma unroll
                for (int mt = 0; mt < 4; ++mt) {
                    f32x4 v = av[mt] + bz;
                    *(f32x4*)&s_u.lg[mt * 16 + l16][qb] = v;
                }
            }
        }
    }
    __syncthreads();

    // ---- softmax over O=5 per (s,q), write out ----
    if (tid < TILE * NQ) {
        int s = tid / NQ, qq = tid - s * NQ;
        int r = s_rows[s];
        if (r >= 0) {
            float l[NO], mx = -1e30f;
#pragma unroll
            for (int o = 0; o < NO; ++o) {
                l[o] = s_u.lg[s][qq * NO + o];
                mx = l[o] > mx ? l[o] : mx;
            }
            float sum = 0.f, e[NO];
#pragma unroll
            for (int o = 0; o < NO; ++o) { e[o] = __expf(l[o] - mx); sum += e[o]; }
            float inv = 1.f / sum;
            float* op = out + (size_t)r * QO + qq * NO;
#pragma unroll
            for (int o = 0; o < NO; ++o) op[o] = e[o] * inv;
        }
    }
}

// ---------------------------------------------------------------------------
extern "C" void kernel_launch(void* const* d_in, const int* in_sizes, int n_in,
                              void* d_out, int out_size, void* d_ws, size_t ws_size,
                              hipStream_t stream)
{
    const float* x     = (const float*)d_in[0];
    const int*   ids   = (const int*)d_in[1];
    const float* W1_w  = (const float*)d_in[2];
    const float* W1_b  = (const float*)d_in[3];
    const float* W2_w  = (const float*)d_in[4];
    const float* W2_b  = (const float*)d_in[5];
    const float* W1a_w = (const float*)d_in[6];
    const float* W1a_b = (const float*)d_in[7];
    const float* W2a_w = (const float*)d_in[8];
    const float* W2a_b = (const float*)d_in[9];
    const float* V_w   = (const float*)d_in[10];
    const float* V_b   = (const float*)d_in[11];
    const float* Va_w  = (const float*)d_in[12];
    const float* Va_b  = (const float*)d_in[13];
    float* out = (float*)d_out;

    char* ws = (char*)d_ws;
    size_t off = 0;
    auto take = [&](size_t nbytes) -> void* {
        void* p = ws + off;
        off = (off + nbytes + 255) & ~(size_t)255;
        return p;
    };
    unsigned short* w1c = (unsigned short*)take((size_t)NJ * 256 * 64 * 2);
    unsigned short* w2c = (unsigned short*)take((size_t)NJ * 256 * 256 * 2);
    unsigned short* vc  = (unsigned short*)take((size_t)NJ * 48 * 256 * 2);
    float* bias1        = (float*)take((size_t)NJ * 256 * 4);
    float* bias2        = (float*)take((size_t)NJ * 256 * 4);
    float* biasv        = (float*)take((size_t)NJ * 48 * 4);
    int* cursor         = (int*)take(NJ * 4);
    int* ntiles         = (int*)take(4);
    int* tileExpert     = (int*)take(MAXT * 4);
    int* perm           = (int*)take((size_t)MAXSLOTS * 4);

    k_prep<<<768, 256, 0, stream>>>(ids, W1_w, W1_b, W2_w, W2_b, W1a_w, W1a_b,
                                    W2a_w, W2a_b, V_w, V_b, Va_w, Va_b,
                                    w1c, w2c, vc, bias1, bias2, biasv,
                                    cursor, ntiles, tileExpert, perm);
    k_scatter<<<(B_N + 255) / 256, 256, 0, stream>>>(ids, cursor, perm);
    k_main<<<MAXT, 512, 0, stream>>>(x, out, perm, ntiles, tileExpert,
                                     w1c, w2c, vc, bias1, bias2, biasv);
}